// Round 3
// baseline (633.708 us; speedup 1.0000x reference)
//
#include <hip/hip_runtime.h>

// BNB 8-bit embedding dequant-on-gather.
// out[t, d] = code[q_idx_flat[x[t]*1024 + d]] * absmax[x[t]/64, (x[t]%64)>>2]
//
// blk = (local*1024 + d)//4096 is constant over d in [0,1024) -> blk = local>>2,
// so scale is one scalar per token.
//
// R1: block-per-token had 1 outstanding 1KB load/wave -> MLP-starved (~300us vs
// ~41us floor). R2: 8 tokens/block -> each wave issues 8 independent dwordx4
// loads before consuming; x/absmax prefetched; nontemporal stores (via native
// ext_vector_type -- HIP float4 class is rejected by the builtin).

#define EMBED_DIM 1024
#define T_PER_BLOCK 8

typedef float vfloat4 __attribute__((ext_vector_type(4)));
typedef int   vint4   __attribute__((ext_vector_type(4)));

__global__ __launch_bounds__(256) void bnb8_embed_kernel(
    const int*   __restrict__ x,
    const int*   __restrict__ q_idx,    // [2000*64*1024] flat
    const float* __restrict__ absmax,   // [2000*16] flat
    const float* __restrict__ code,     // [256]
    float*       __restrict__ out,      // [n_tokens*1024]
    int n_tokens)
{
    __shared__ float code_lds[256];
    const int tid = threadIdx.x;        // 0..255
    code_lds[tid] = code[tid];

    const int tbase = blockIdx.x * T_PER_BLOCK;

    // Prefetch token ids + scales (wave-uniform -> scalar loads, independent).
    int   xv[T_PER_BLOCK];
    float sc[T_PER_BLOCK];
#pragma unroll
    for (int t = 0; t < T_PER_BLOCK; ++t) {
        const int tok = tbase + t;
        xv[t] = (tok < n_tokens) ? x[tok] : 0;
    }
#pragma unroll
    for (int t = 0; t < T_PER_BLOCK; ++t) {
        sc[t] = absmax[(xv[t] >> 6) * 16 + ((xv[t] & 63) >> 2)];
    }

    // Issue all 8 independent 16B row-segment loads back-to-back (8KB/wave MLP).
    vint4 q[T_PER_BLOCK];
#pragma unroll
    for (int t = 0; t < T_PER_BLOCK; ++t) {
        q[t] = ((const vint4*)(q_idx + (size_t)xv[t] * EMBED_DIM))[tid];
    }

    __syncthreads();   // code_lds ready (placed after load issue: no dependency)

#pragma unroll
    for (int t = 0; t < T_PER_BLOCK; ++t) {
        const int tok = tbase + t;
        if (tok < n_tokens) {
            vfloat4 v;
            v.x = code_lds[q[t].x] * sc[t];
            v.y = code_lds[q[t].y] * sc[t];
            v.z = code_lds[q[t].z] * sc[t];
            v.w = code_lds[q[t].w] * sc[t];
            __builtin_nontemporal_store(v, ((vfloat4*)(out + (size_t)tok * EMBED_DIM)) + tid);
        }
    }
}

extern "C" void kernel_launch(void* const* d_in, const int* in_sizes, int n_in,
                              void* d_out, int out_size, void* d_ws, size_t ws_size,
                              hipStream_t stream) {
    const int*   x      = (const int*)d_in[0];    // [8*4096]
    const int*   q_idx  = (const int*)d_in[1];    // [2000,64,1024]
    const float* absmax = (const float*)d_in[2];  // [2000,16]
    const float* code   = (const float*)d_in[3];  // [256]
    float*       out    = (float*)d_out;          // [8,4096,1024] fp32

    const int n_tokens = in_sizes[0];             // 32768
    const int n_blocks = (n_tokens + T_PER_BLOCK - 1) / T_PER_BLOCK;
    bnb8_embed_kernel<<<n_blocks, 256, 0, stream>>>(x, q_idx, absmax, code, out, n_tokens);
}